// Round 1
// 124.775 us; speedup vs baseline: 1.0219x; 1.0219x over previous
//
#include <hip/hip_runtime.h>
#include <stdint.h>

#define NT 2048
#define DT 128

typedef __bf16 bf16x8 __attribute__((ext_vector_type(8)));
typedef __bf16 bf16x4 __attribute__((ext_vector_type(4)));
typedef float  f32x16 __attribute__((ext_vector_type(16)));

// ============================================================================
// prep: one-shot dtype/layout conversion.
//   blocks 0..511    : Qt[b][n][d] = bf16(Q[b][d][n])   (64x64 LDS transpose)
//   blocks 512..1023 : Kt[b][m][d] = bf16(K[b][d][m])
//   blocks 1024..2047: Vb[b][v][n] = bf16(V[b][v][n])   (straight convert)
// ============================================================================
__global__ __launch_bounds__(256)
void prep(const float* __restrict__ Q, const float* __restrict__ K,
          const float* __restrict__ V,
          __bf16* __restrict__ Qt, __bf16* __restrict__ Kt, __bf16* __restrict__ Vb)
{
    const int bid = blockIdx.x;
    const int t   = threadIdx.x;
    if (bid < 1024) {
        __shared__ float ls[64][65];            // +1 pad: conflict-free transpose
        const float* src = (bid < 512) ? Q : K;
        __bf16*      dst = (bid < 512) ? Qt : Kt;
        const int idx = bid & 511;
        const int b   = idx >> 6;               // 0..7
        const int di  = (idx >> 5) & 1;         // d-tile 0..1
        const int ni  = idx & 31;               // n-tile 0..31
        const int d0 = di * 64, n0 = ni * 64;
        const float* sb = src + (size_t)b * DT * NT;
        #pragma unroll
        for (int rr = 0; rr < 4; ++rr) {
            const int dl = (t >> 4) + 16 * rr;
            const float4 v4 = *(const float4*)(sb + (size_t)(d0 + dl) * NT + n0 + 4 * (t & 15));
            ls[dl][4 * (t & 15) + 0] = v4.x;
            ls[dl][4 * (t & 15) + 1] = v4.y;
            ls[dl][4 * (t & 15) + 2] = v4.z;
            ls[dl][4 * (t & 15) + 3] = v4.w;
        }
        __syncthreads();
        __bf16* db = dst + (size_t)b * NT * DT;
        #pragma unroll
        for (int rr = 0; rr < 4; ++rr) {
            const int nl = (t >> 4) + 16 * rr;
            bf16x4 pk;
            #pragma unroll
            for (int j = 0; j < 4; ++j) pk[j] = (__bf16)ls[4 * (t & 15) + j][nl];
            *(bf16x4*)(db + (size_t)(n0 + nl) * DT + d0 + 4 * (t & 15)) = pk;
        }
    } else {
        const int vb = bid - 1024;
        const size_t base = (size_t)vb * 2048 + (size_t)t * 8;
        const float4 a = *(const float4*)(V + base);
        const float4 c = *(const float4*)(V + base + 4);
        bf16x8 pk;
        pk[0] = (__bf16)a.x; pk[1] = (__bf16)a.y; pk[2] = (__bf16)a.z; pk[3] = (__bf16)a.w;
        pk[4] = (__bf16)c.x; pk[5] = (__bf16)c.y; pk[6] = (__bf16)c.z; pk[7] = (__bf16)c.w;
        *(bf16x8*)(Vb + base) = pk;
    }
}

// ============================================================================
// sig_attn2: n-chunk 128, 4 iterations, 8 barriers/block (was 16), V direct
// from global bf16 (no Vs LDS), Q staged from pre-transposed Qt, K frags from
// pre-transposed Kt. Same grid / bid decode / partial-ws layout as v1 so
// reduce4 is unchanged.
//   mfma_f32_32x32x16_bf16:
//     A: lane holds A[row=lane&31][k=(lane>>5)*8+j]
//     B: lane holds B[k=(lane>>5)*8+j][col=lane&31]
//     C/D: col=lane&31, row=(reg&3)+8*(reg>>2)+4*(lane>>5)
// ============================================================================
__global__ __launch_bounds__(512, 4)
void sig_attn2(const __bf16* __restrict__ Qt, const __bf16* __restrict__ Kt,
               const __bf16* __restrict__ Vb, float* __restrict__ wsp)
{
    __shared__ __align__(16) __bf16 Qs[128 * 128];   // [n][d], 16B granule g at slot g^(n&15)
    __shared__ __align__(16) __bf16 Ss[128 * 128];   // [m][n], 16B granule g at slot g^(m&15)

    const int t   = threadIdx.x;
    const int w   = t >> 6;       // wave 0..7
    const int l   = t & 63;
    const int lq  = l >> 5;
    const int l31 = l & 31;
    const int wm  = w & 3;        // 32-wide m-column
    const int wv  = w >> 2;       // GEMM1 n-pair selector / GEMM2 v-half

    const int bid   = blockIdx.x;
    const int b     = bid & 7;           // XCD-pinned batch
    const int mt    = (bid >> 3) & 15;
    const int ns    = bid >> 7;          // 0..3
    const int m_blk = mt * 128;
    const int n_base = ns * 512;

    const __bf16* Qtb = Qt + (size_t)b * NT * DT;
    const __bf16* Ktb = Kt + (size_t)b * NT * DT;
    const __bf16* Vbb = Vb + (size_t)b * DT * NT;

    const int mrow = 32 * wm + l31;      // local m within 128-tile

    // ---- K -> register B-fragments: kf[k][j] = K[d=16k+8lq+j][m_blk+mrow]
    bf16x8 kf[8];
    #pragma unroll
    for (int k = 0; k < 8; ++k)
        kf[k] = *(const bf16x8*)(Ktb + (size_t)(m_blk + mrow) * DT + 16 * k + 8 * lq);

    // ---- stage Qs chunk 0: thread owns row srow, 4 contiguous 16B granules
    const int srow = t >> 2;             // 0..127
    const int scol = t & 3;
    {
        const __bf16* qsrc = Qtb + (size_t)(n_base + srow) * DT + 32 * scol;
        #pragma unroll
        for (int j = 0; j < 4; ++j) {
            const bf16x8 q = *(const bf16x8*)(qsrc + 8 * j);
            *(bf16x8*)&Qs[srow * 128 + ((4 * scol + j) ^ (srow & 15)) * 8] = q;
        }
    }

    f32x16 oacc[2];
    #pragma unroll
    for (int tv = 0; tv < 2; ++tv)
        #pragma unroll
        for (int r = 0; r < 16; ++r) oacc[tv][r] = 0.0f;

    __syncthreads();                     // Qs(0) visible

    bf16x8 qpre[4];
    for (int it = 0; it < 4; ++it) {
        const int n0 = n_base + it * 128;

        // ---- GEMM1: two independent 32x32 S-tiles (nidx = wv, wv+2), K=128d
        f32x16 s0, s1;
        #pragma unroll
        for (int r = 0; r < 16; ++r) { s0[r] = 0.0f; s1[r] = 0.0f; }
        const int row0 = 32 * wv + l31;
        const int row1 = row0 + 64;
        #pragma unroll
        for (int k = 0; k < 8; ++k) {
            const int g = 2 * k + lq;
            const bf16x8 a0 = *(const bf16x8*)&Qs[row0 * 128 + (g ^ (row0 & 15)) * 8];
            const bf16x8 a1 = *(const bf16x8*)&Qs[row1 * 128 + (g ^ (row1 & 15)) * 8];
            s0 = __builtin_amdgcn_mfma_f32_32x32x16_bf16(a0, kf[k], s0, 0, 0, 0);
            s1 = __builtin_amdgcn_mfma_f32_32x32x16_bf16(a1, kf[k], s1, 0, 0, 0);
        }

        // ---- prefetch next Q chunk into regs (hidden under sigmoid + B2)
        if (it < 3) {
            const __bf16* qsrc = Qtb + (size_t)(n0 + 128 + srow) * DT + 32 * scol;
            #pragma unroll
            for (int j = 0; j < 4; ++j) qpre[j] = *(const bf16x8*)(qsrc + 8 * j);
        }

        // ---- sigmoid(x/sqrt(128)) -> Ss[m][n]
        #pragma unroll
        for (int g = 0; g < 4; ++g) {
            bf16x4 p0, p1;
            #pragma unroll
            for (int rr = 0; rr < 4; ++rr) {
                const float e0 = __expf(s0[4 * g + rr] * -0.08838834764831845f);
                p0[rr] = (__bf16)__builtin_amdgcn_rcpf(1.0f + e0);
                const float e1 = __expf(s1[4 * g + rr] * -0.08838834764831845f);
                p1[rr] = (__bf16)__builtin_amdgcn_rcpf(1.0f + e1);
            }
            *(bf16x4*)&Ss[mrow * 128 + (((4 * wv + g)       ^ (mrow & 15)) * 8) + 4 * lq] = p0;
            *(bf16x4*)&Ss[mrow * 128 + (((4 * (wv + 2) + g) ^ (mrow & 15)) * 8) + 4 * lq] = p1;
        }
        __syncthreads();   // B2: Ss ready; all waves done reading Qs(it)

        // ---- write next Q chunk into Qs (consumed after B1 below)
        if (it < 3) {
            #pragma unroll
            for (int j = 0; j < 4; ++j)
                *(bf16x8*)&Qs[srow * 128 + ((4 * scol + j) ^ (srow & 15)) * 8] = qpre[j];
        }

        // ---- GEMM2: oacc += V * S, K = 128 n; V A-frags direct from global bf16
        const __bf16* v0p = Vbb + (size_t)(64 * wv + l31) * NT + n0 + 8 * lq;
        #pragma unroll
        for (int k = 0; k < 8; ++k) {
            const bf16x8 av0 = *(const bf16x8*)(v0p + 16 * k);
            const bf16x8 av1 = *(const bf16x8*)(v0p + (size_t)32 * NT + 16 * k);
            const bf16x8 bs  = *(const bf16x8*)&Ss[mrow * 128 + ((2 * k + lq) ^ (mrow & 15)) * 8];
            oacc[0] = __builtin_amdgcn_mfma_f32_32x32x16_bf16(av0, bs, oacc[0], 0, 0, 0);
            oacc[1] = __builtin_amdgcn_mfma_f32_32x32x16_bf16(av1, bs, oacc[1], 0, 0, 0);
        }
        if (it < 3) __syncthreads();   // B1 for next iter: Qs(it+1) visible, Ss free
    }

    // ---- epilogue: per-block partial [v 128][m 128] (same layout as v1)
    float* wsb = wsp + (size_t)bid * 16384;
    #pragma unroll
    for (int tv = 0; tv < 2; ++tv) {
        #pragma unroll
        for (int r = 0; r < 16; ++r) {
            const int v = 64 * wv + 32 * tv + (r & 3) + 8 * (r >> 2) + 4 * lq;
            wsb[v * 128 + mrow] = oacc[tv][r];
        }
    }
}

// ============================================================================
// v1 kernel kept verbatim as fallback for small-ws harnesses
// ============================================================================
template <int WSMODE>
__global__ __launch_bounds__(512, 4)
void sig_attn(const float* __restrict__ Q, const float* __restrict__ K,
              const float* __restrict__ V, float* __restrict__ outp)
{
    __shared__ __align__(16) __bf16 Qs[64 * 128];
    __shared__ __align__(16) __bf16 Ss[128 * 64];
    __shared__ __align__(16) __bf16 Vs[2][128 * 64];

    const int t   = threadIdx.x;
    const int w   = t >> 6;
    const int l   = t & 63;
    const int lq  = l >> 5;
    const int l31 = l & 31;
    const int wm  = w & 3;
    const int wn  = w >> 2;

    const int bid    = blockIdx.x;
    const int b      = bid & 7;
    const int mt     = (bid >> 3) & 15;
    const int ns     = bid >> 7;
    const int m_blk  = mt * 128;
    const int n_base = ns * 512;

    const float* Qb = Q + (size_t)b * DT * NT;
    const float* Kb = K + (size_t)b * DT * NT;
    const float* Vb = V + (size_t)b * DT * NT;

    const int mrow = 32 * wm + l31;

    bf16x8 kf[8];
    #pragma unroll
    for (int half = 0; half < 2; ++half) {
        float tmp[4][8];
        #pragma unroll
        for (int k2 = 0; k2 < 4; ++k2)
            #pragma unroll
            for (int j = 0; j < 8; ++j)
                tmp[k2][j] = Kb[(size_t)((half * 4 + k2) * 16 + lq * 8 + j) * NT + m_blk + mrow];
        #pragma unroll
        for (int k2 = 0; k2 < 4; ++k2) {
            bf16x8 f;
            #pragma unroll
            for (int j = 0; j < 8; ++j) f[j] = (__bf16)tmp[k2][j];
            kf[half * 4 + k2] = f;
        }
    }

    f32x16 oacc[2];
    #pragma unroll
    for (int tv = 0; tv < 2; ++tv)
        #pragma unroll
        for (int r = 0; r < 16; ++r)
            oacc[tv][r] = 0.0f;

    float qp[16];
    #pragma unroll
    for (int r = 0; r < 2; ++r)
        #pragma unroll
        for (int j = 0; j < 8; ++j)
            qp[r * 8 + j] = Qb[(size_t)(64 * r + 8 * w + j) * NT + n_base + l];
    float4 vp[4];
    #pragma unroll
    for (int p = 0; p < 4; ++p)
        vp[p] = *(const float4*)(Vb + (size_t)(p * 32 + (t >> 4)) * NT + n_base + 4 * (t & 15));

    for (int it = 0; it < 8; ++it) {
        __bf16* Vbuf = Vs[it & 1];

        #pragma unroll
        for (int r = 0; r < 2; ++r) {
            bf16x8 pk;
            #pragma unroll
            for (int j = 0; j < 8; ++j) pk[j] = (__bf16)qp[r * 8 + j];
            *(bf16x8*)&Qs[l * 128 + ((8 * r + w) ^ (l & 15)) * 8] = pk;
        }
        #pragma unroll
        for (int p = 0; p < 4; ++p) {
            const int v  = p * 32 + (t >> 4);
            const int ng = t & 15;
            bf16x4 pk;
            pk[0] = (__bf16)vp[p].x;
            pk[1] = (__bf16)vp[p].y;
            pk[2] = (__bf16)vp[p].z;
            pk[3] = (__bf16)vp[p].w;
            *(bf16x4*)&Vbuf[v * 64 + ((ng >> 1) ^ (v & 7)) * 8 + 4 * (ng & 1)] = pk;
        }
        __syncthreads();

        const int n0n = n_base + ((it + 1) & 7) * 64;
        #pragma unroll
        for (int r = 0; r < 2; ++r)
            #pragma unroll
            for (int j = 0; j < 8; ++j)
                qp[r * 8 + j] = Qb[(size_t)(64 * r + 8 * w + j) * NT + n0n + l];
        #pragma unroll
        for (int p = 0; p < 4; ++p)
            vp[p] = *(const float4*)(Vb + (size_t)(p * 32 + (t >> 4)) * NT + n0n + 4 * (t & 15));

        f32x16 sacc;
        #pragma unroll
        for (int r = 0; r < 16; ++r) sacc[r] = 0.0f;
        const int nrow = 32 * wn + l31;
        #pragma unroll
        for (int k = 0; k < 8; ++k) {
            const bf16x8 af =
                *(const bf16x8*)&Qs[nrow * 128 + ((2 * k + lq) ^ (nrow & 15)) * 8];
            sacc = __builtin_amdgcn_mfma_f32_32x32x16_bf16(af, kf[k], sacc, 0, 0, 0);
        }

        #pragma unroll
        for (int g = 0; g < 4; ++g) {
            bf16x4 pk;
            #pragma unroll
            for (int rr = 0; rr < 4; ++rr) {
                const float x = sacc[4 * g + rr];
                const float e = __expf(x * -0.08838834764831845f);
                pk[rr] = (__bf16)__builtin_amdgcn_rcpf(1.0f + e);
            }
            *(bf16x4*)&Ss[mrow * 64 + ((4 * wn + g) ^ (mrow & 7)) * 8 + 4 * lq] = pk;
        }
        __syncthreads();

        #pragma unroll
        for (int k = 0; k < 4; ++k) {
            const int sw = 2 * k + lq;
            const bf16x8 av0 =
                *(const bf16x8*)&Vbuf[(64 * wn + l31) * 64 + (sw ^ (l31 & 7)) * 8];
            const bf16x8 av1 =
                *(const bf16x8*)&Vbuf[(64 * wn + 32 + l31) * 64 + (sw ^ (l31 & 7)) * 8];
            const bf16x8 bs =
                *(const bf16x8*)&Ss[mrow * 64 + (sw ^ (mrow & 7)) * 8];
            oacc[0] = __builtin_amdgcn_mfma_f32_32x32x16_bf16(av0, bs, oacc[0], 0, 0, 0);
            oacc[1] = __builtin_amdgcn_mfma_f32_32x32x16_bf16(av1, bs, oacc[1], 0, 0, 0);
        }
    }

    if (WSMODE == 0) {
        float* wsb = outp + (size_t)bid * 16384;
        #pragma unroll
        for (int tv = 0; tv < 2; ++tv) {
            #pragma unroll
            for (int r = 0; r < 16; ++r) {
                const int v = 64 * wn + 32 * tv + (r & 3) + 8 * (r >> 2) + 4 * lq;
                wsb[v * 128 + mrow] = oacc[tv][r];
            }
        }
    } else {
        float* Ob = outp + (size_t)b * DT * NT;
        #pragma unroll
        for (int tv = 0; tv < 2; ++tv) {
            #pragma unroll
            for (int r = 0; r < 16; ++r) {
                const int v = 64 * wn + 32 * tv + (r & 3) + 8 * (r >> 2) + 4 * lq;
                atomicAdd(&Ob[(size_t)v * NT + m_blk + mrow], oacc[tv][r]);
            }
        }
    }
}

// out[o] = sum over 4 n-splits of ws partials; float4 per thread, fully coalesced
__global__ __launch_bounds__(256)
void reduce4(const float4* __restrict__ ws, float4* __restrict__ out)
{
    const int i = blockIdx.x * 256 + threadIdx.x;
    const int o = i * 4;
    const int m_glob = o & 2047;
    const int vb     = o >> 11;
    const int v      = vb & 127;
    const int bb     = vb >> 7;
    const int mt     = m_glob >> 7;
    const int m      = m_glob & 127;
    const size_t base = ((size_t)(bb + 8 * mt) * 16384 + (size_t)v * 128 + m) >> 2;
    const size_t strd = 524288;
    float4 a = ws[base];
    float4 c = ws[base + strd];
    float4 d = ws[base + 2 * strd];
    float4 e = ws[base + 3 * strd];
    float4 r;
    r.x = a.x + c.x + d.x + e.x;
    r.y = a.y + c.y + d.y + e.y;
    r.z = a.z + c.z + d.z + e.z;
    r.w = a.w + c.w + d.w + e.w;
    out[i] = r;
}

extern "C" void kernel_launch(void* const* d_in, const int* in_sizes, int n_in,
                              void* d_out, int out_size, void* d_ws, size_t ws_size,
                              hipStream_t stream) {
    (void)in_sizes; (void)n_in;
    const float* Q = (const float*)d_in[0];
    const float* K = (const float*)d_in[1];
    const float* V = (const float*)d_in[2];
    const size_t PART  = (size_t)512 * 16384 * 4;          // 33.5 MB fp32 partials
    const size_t CONV  = (size_t)3 * 8 * NT * DT * 2;      // 12.6 MB bf16 Qt/Kt/Vb
    if (ws_size >= PART + CONV) {
        __bf16* Qt = (__bf16*)((char*)d_ws + PART);
        __bf16* Kt = Qt + (size_t)8 * NT * DT;
        __bf16* Vb = Kt + (size_t)8 * NT * DT;
        prep<<<dim3(2048), dim3(256), 0, stream>>>(Q, K, V, Qt, Kt, Vb);
        sig_attn2<<<dim3(512), dim3(512), 0, stream>>>(Qt, Kt, Vb, (float*)d_ws);
        reduce4<<<dim3(2048), dim3(256), 0, stream>>>((const float4*)d_ws, (float4*)d_out);
    } else if (ws_size >= PART) {
        sig_attn<0><<<dim3(512), dim3(512), 0, stream>>>(Q, K, V, (float*)d_ws);
        reduce4<<<dim3(2048), dim3(256), 0, stream>>>((const float4*)d_ws, (float4*)d_out);
    } else {
        hipMemsetAsync(d_out, 0, (size_t)out_size * sizeof(float), stream);
        sig_attn<1><<<dim3(512), dim3(512), 0, stream>>>(Q, K, V, (float*)d_out);
    }
}